// Round 8
// baseline (1813.531 us; speedup 1.0000x reference)
//
#include <hip/hip_runtime.h>
#include <math.h>

// ---------------------------------------------------------------------------
// Problem: N=2048, M=2048, D=1024, EMB=64, HEADS=16
//   q   = ref_feat @ Wq_w.T + Wq_b            [N,D]
//   k   = sup_feat @ Wk_w.T + Wk_b            [M,D]
//   aff = (q @ k.T) / 32                      [N,M]
//   pos[h,n,m] = relu(sum_e Wg_w[h,e]*PE[e,n,m] + Wg_b[h])
//   out[n,m] = ( mean_h sigmoid(log(pos+1e-6)+aff) > 0.5 ) ? 1 : 0
// Identity: sigmoid(log(w')+a) = w' / (w' + exp(-a)),  w' = relu(x)+1e-6
// All fp32 (binary threshold output => bf16 MFMA would flip boundary bits).
//
// R3 structure (occupancy-driven rework of R2):
//   R2 ran 256 blocks / 256 threads = 1 wave/SIMD everywhere -> all LDS and
//   HBM latency exposed. R3:
//   K1 gemm_qk : 64x128 tiles, BK=32 -> 512 blocks = 2 blocks/CU, half the
//                barriers. Per-output fmaf chain still k-ascending (bitwise
//                identical to R2).
//   K2 gemm_e  : aff GEMM, same 64x128 shape; epilogue writes
//                E = exp(-aff/32) to HBM (16 MB) instead of LDS.
//   K3 gate_out: pure streaming kernel, no LDS, 4096 blocks, 8-deep load
//                pipeline -> PE (1.07 GB) at HBM rate. Gating math op-for-op
//                identical to R2 phase 2.
// ---------------------------------------------------------------------------

#define GN 2048
#define GM 2048
#define GD 1024
#define GEMB 64
#define GHEADS 16
#define CHANSTRIDE ((size_t)GN * GM)   // floats per PE channel

#define BM 64
#define BN 128
#define BK 32
#define LDA (BM + 4)   // padded LDS leading dims (floats)
#define LDB (BN + 4)

// ---------------- K1: q,k GEMM (C = A @ B^T + bias), 2 blocks/CU ------------
__global__ __launch_bounds__(256) void gemm_qk(const float* __restrict__ ref,
                                               const float* __restrict__ sup,
                                               const float* __restrict__ Wq_w,
                                               const float* __restrict__ Wq_b,
                                               const float* __restrict__ Wk_w,
                                               const float* __restrict__ Wk_b,
                                               const float* __restrict__ Wg_w,
                                               float* __restrict__ q,
                                               float* __restrict__ k,
                                               float* __restrict__ wT) {
    __shared__ float As[BK][LDA];
    __shared__ float Bs[BK][LDB];

    const int z = blockIdx.z;
    const float* A    = z ? sup  : ref;
    const float* B    = z ? Wk_w : Wq_w;
    const float* bias = z ? Wk_b : Wq_b;
    float*       C    = z ? k    : q;

    const int t  = threadIdx.x;
    const int tx = t & 15;
    const int ty = t >> 4;
    const int row0 = blockIdx.y * BM;
    const int col0 = blockIdx.x * BN;

    // one block transposes the 16x64 gate weights into ws (wT[e*16+h])
    if (z == 0 && blockIdx.x == 0 && blockIdx.y == 0 && t < GEMB) {
#pragma unroll
        for (int h = 0; h < GHEADS; ++h) wT[t * GHEADS + h] = Wg_w[h * GEMB + t];
    }

    float acc[4][8];
#pragma unroll
    for (int i = 0; i < 4; ++i)
#pragma unroll
        for (int j = 0; j < 8; ++j) acc[i][j] = 0.0f;

    // staging: A tile 64x32 = 512 float4 (2/thread), B tile 128x32 = 1024 (4/thread)
    float4 pa[2], pb[4];
#pragma unroll
    for (int i = 0; i < 2; ++i) {
        const int idx = t + i * 256;
        pa[i] = *(const float4*)&A[(size_t)(row0 + (idx >> 3)) * GD + ((idx & 7) << 2)];
    }
#pragma unroll
    for (int i = 0; i < 4; ++i) {
        const int idx = t + i * 256;
        pb[i] = *(const float4*)&B[(size_t)(col0 + (idx >> 3)) * GD + ((idx & 7) << 2)];
    }
#pragma unroll
    for (int i = 0; i < 2; ++i) {
        const int idx = t + i * 256;
        const int r = idx >> 3, c4 = (idx & 7) << 2;
        As[c4 + 0][r] = pa[i].x; As[c4 + 1][r] = pa[i].y;
        As[c4 + 2][r] = pa[i].z; As[c4 + 3][r] = pa[i].w;
    }
#pragma unroll
    for (int i = 0; i < 4; ++i) {
        const int idx = t + i * 256;
        const int r = idx >> 3, c4 = (idx & 7) << 2;
        Bs[c4 + 0][r] = pb[i].x; Bs[c4 + 1][r] = pb[i].y;
        Bs[c4 + 2][r] = pb[i].z; Bs[c4 + 3][r] = pb[i].w;
    }
    __syncthreads();

    for (int k0 = 0; k0 < GD; k0 += BK) {
        const bool more = (k0 + BK) < GD;
        if (more) {
#pragma unroll
            for (int i = 0; i < 2; ++i) {
                const int idx = t + i * 256;
                pa[i] = *(const float4*)&A[(size_t)(row0 + (idx >> 3)) * GD + k0 + BK + ((idx & 7) << 2)];
            }
#pragma unroll
            for (int i = 0; i < 4; ++i) {
                const int idx = t + i * 256;
                pb[i] = *(const float4*)&B[(size_t)(col0 + (idx >> 3)) * GD + k0 + BK + ((idx & 7) << 2)];
            }
        }
#pragma unroll
        for (int kk = 0; kk < BK; ++kk) {
            float a[4], b[8];
            *(float4*)&a[0] = *(const float4*)&As[kk][ty * 4];
            *(float4*)&b[0] = *(const float4*)&Bs[kk][tx * 8];
            *(float4*)&b[4] = *(const float4*)&Bs[kk][tx * 8 + 4];
#pragma unroll
            for (int i = 0; i < 4; ++i)
#pragma unroll
                for (int j = 0; j < 8; ++j) acc[i][j] = fmaf(a[i], b[j], acc[i][j]);
        }
        __syncthreads();
        if (more) {
#pragma unroll
            for (int i = 0; i < 2; ++i) {
                const int idx = t + i * 256;
                const int r = idx >> 3, c4 = (idx & 7) << 2;
                As[c4 + 0][r] = pa[i].x; As[c4 + 1][r] = pa[i].y;
                As[c4 + 2][r] = pa[i].z; As[c4 + 3][r] = pa[i].w;
            }
#pragma unroll
            for (int i = 0; i < 4; ++i) {
                const int idx = t + i * 256;
                const int r = idx >> 3, c4 = (idx & 7) << 2;
                Bs[c4 + 0][r] = pb[i].x; Bs[c4 + 1][r] = pb[i].y;
                Bs[c4 + 2][r] = pb[i].z; Bs[c4 + 3][r] = pb[i].w;
            }
        }
        __syncthreads();
    }

#pragma unroll
    for (int i = 0; i < 4; ++i) {
        const int r = row0 + ty * 4 + i;
#pragma unroll
        for (int j = 0; j < 8; j += 4) {
            const int c = col0 + tx * 8 + j;
            float4 v;
            v.x = acc[i][j + 0] + bias[c + 0];
            v.y = acc[i][j + 1] + bias[c + 1];
            v.z = acc[i][j + 2] + bias[c + 2];
            v.w = acc[i][j + 3] + bias[c + 3];
            *(float4*)&C[(size_t)r * GD + c] = v;
        }
    }
}

// ---------------- K2: aff GEMM -> E = exp(-aff/32) to HBM -------------------
__global__ __launch_bounds__(256) void gemm_e(const float* __restrict__ q,
                                              const float* __restrict__ k,
                                              float* __restrict__ E) {
    __shared__ float As[BK][LDA];
    __shared__ float Bs[BK][LDB];

    const int t  = threadIdx.x;
    const int tx = t & 15;
    const int ty = t >> 4;
    const int n0 = blockIdx.y * BM;
    const int m0 = blockIdx.x * BN;

    float acc[4][8];
#pragma unroll
    for (int i = 0; i < 4; ++i)
#pragma unroll
        for (int j = 0; j < 8; ++j) acc[i][j] = 0.0f;

    float4 pa[2], pb[4];
#pragma unroll
    for (int i = 0; i < 2; ++i) {
        const int idx = t + i * 256;
        pa[i] = *(const float4*)&q[(size_t)(n0 + (idx >> 3)) * GD + ((idx & 7) << 2)];
    }
#pragma unroll
    for (int i = 0; i < 4; ++i) {
        const int idx = t + i * 256;
        pb[i] = *(const float4*)&k[(size_t)(m0 + (idx >> 3)) * GD + ((idx & 7) << 2)];
    }
#pragma unroll
    for (int i = 0; i < 2; ++i) {
        const int idx = t + i * 256;
        const int r = idx >> 3, c4 = (idx & 7) << 2;
        As[c4 + 0][r] = pa[i].x; As[c4 + 1][r] = pa[i].y;
        As[c4 + 2][r] = pa[i].z; As[c4 + 3][r] = pa[i].w;
    }
#pragma unroll
    for (int i = 0; i < 4; ++i) {
        const int idx = t + i * 256;
        const int r = idx >> 3, c4 = (idx & 7) << 2;
        Bs[c4 + 0][r] = pb[i].x; Bs[c4 + 1][r] = pb[i].y;
        Bs[c4 + 2][r] = pb[i].z; Bs[c4 + 3][r] = pb[i].w;
    }
    __syncthreads();

    for (int k0 = 0; k0 < GD; k0 += BK) {
        const bool more = (k0 + BK) < GD;
        if (more) {
#pragma unroll
            for (int i = 0; i < 2; ++i) {
                const int idx = t + i * 256;
                pa[i] = *(const float4*)&q[(size_t)(n0 + (idx >> 3)) * GD + k0 + BK + ((idx & 7) << 2)];
            }
#pragma unroll
            for (int i = 0; i < 4; ++i) {
                const int idx = t + i * 256;
                pb[i] = *(const float4*)&k[(size_t)(m0 + (idx >> 3)) * GD + k0 + BK + ((idx & 7) << 2)];
            }
        }
#pragma unroll
        for (int kk = 0; kk < BK; ++kk) {
            float a[4], b[8];
            *(float4*)&a[0] = *(const float4*)&As[kk][ty * 4];
            *(float4*)&b[0] = *(const float4*)&Bs[kk][tx * 8];
            *(float4*)&b[4] = *(const float4*)&Bs[kk][tx * 8 + 4];
#pragma unroll
            for (int i = 0; i < 4; ++i)
#pragma unroll
                for (int j = 0; j < 8; ++j) acc[i][j] = fmaf(a[i], b[j], acc[i][j]);
        }
        __syncthreads();
        if (more) {
#pragma unroll
            for (int i = 0; i < 2; ++i) {
                const int idx = t + i * 256;
                const int r = idx >> 3, c4 = (idx & 7) << 2;
                As[c4 + 0][r] = pa[i].x; As[c4 + 1][r] = pa[i].y;
                As[c4 + 2][r] = pa[i].z; As[c4 + 3][r] = pa[i].w;
            }
#pragma unroll
            for (int i = 0; i < 4; ++i) {
                const int idx = t + i * 256;
                const int r = idx >> 3, c4 = (idx & 7) << 2;
                Bs[c4 + 0][r] = pb[i].x; Bs[c4 + 1][r] = pb[i].y;
                Bs[c4 + 2][r] = pb[i].z; Bs[c4 + 3][r] = pb[i].w;
            }
        }
        __syncthreads();
    }

    // E = exp(-aff/32)  (identical expression to R2's LDS fill)
#pragma unroll
    for (int i = 0; i < 4; ++i) {
        const int r = n0 + ty * 4 + i;
#pragma unroll
        for (int j = 0; j < 8; j += 4) {
            const int c = m0 + tx * 8 + j;
            float4 ev;
            ev.x = expf(-acc[i][j + 0] * 0.03125f);
            ev.y = expf(-acc[i][j + 1] * 0.03125f);
            ev.z = expf(-acc[i][j + 2] * 0.03125f);
            ev.w = expf(-acc[i][j + 3] * 0.03125f);
            *(float4*)&E[(size_t)r * GM + c] = ev;
        }
    }
}

// ---------------- K3: stream PE, gate, sigmoid-mean, threshold --------------
// 4096 blocks x 256 threads, no LDS -> ~5 waves/SIMD. Each block: 1024
// consecutive m of one row n; thread owns 4 m. 64 channel loads 16MB apart,
// 8-deep unrolled pipeline. Gating math op-for-op identical to R2 phase 2.
__global__ __launch_bounds__(256) void gate_out(const float* __restrict__ PE,
                                                const float* __restrict__ E,
                                                const float* __restrict__ wT,
                                                const float* __restrict__ Wg_b,
                                                float* __restrict__ out) {
    const int t = threadIdx.x;
    const int n = blockIdx.y;
    const int m = blockIdx.x * 1024 + t * 4;

    const float* peBase = PE + (size_t)n * GM + m;
    const float4 Ev = *(const float4*)&E[(size_t)n * GM + m];

    float4 g[GHEADS];
#pragma unroll
    for (int h = 0; h < GHEADS; ++h) {
        const float b = Wg_b[h];               // uniform -> s_load
        g[h].x = b; g[h].y = b; g[h].z = b; g[h].w = b;
    }
#pragma unroll 8
    for (int e = 0; e < GEMB; ++e) {
        const float4 p = *(const float4*)(peBase + (size_t)e * CHANSTRIDE);
#pragma unroll
        for (int h = 0; h < GHEADS; ++h) {
            const float w = wT[e * GHEADS + h];   // uniform -> s_load
            g[h].x = fmaf(w, p.x, g[h].x);
            g[h].y = fmaf(w, p.y, g[h].y);
            g[h].z = fmaf(w, p.z, g[h].z);
            g[h].w = fmaf(w, p.w, g[h].w);
        }
    }

    float s0 = 0.f, s1 = 0.f, s2 = 0.f, s3 = 0.f;
#pragma unroll
    for (int h = 0; h < GHEADS; ++h) {
        float wp;
        wp = fmaxf(g[h].x, 0.0f) + 1e-6f; s0 += wp * __builtin_amdgcn_rcpf(wp + Ev.x);
        wp = fmaxf(g[h].y, 0.0f) + 1e-6f; s1 += wp * __builtin_amdgcn_rcpf(wp + Ev.y);
        wp = fmaxf(g[h].z, 0.0f) + 1e-6f; s2 += wp * __builtin_amdgcn_rcpf(wp + Ev.z);
        wp = fmaxf(g[h].w, 0.0f) + 1e-6f; s3 += wp * __builtin_amdgcn_rcpf(wp + Ev.w);
    }
    float4 o;
    o.x = (s0 * 0.0625f > 0.5f) ? 1.0f : 0.0f;
    o.y = (s1 * 0.0625f > 0.5f) ? 1.0f : 0.0f;
    o.z = (s2 * 0.0625f > 0.5f) ? 1.0f : 0.0f;
    o.w = (s3 * 0.0625f > 0.5f) ? 1.0f : 0.0f;
    *(float4*)&out[(size_t)n * GM + m] = o;
}

// ---------------------------------------------------------------------------
extern "C" void kernel_launch(void* const* d_in, const int* in_sizes, int n_in,
                              void* d_out, int out_size, void* d_ws, size_t ws_size,
                              hipStream_t stream) {
    const float* ref_feat = (const float*)d_in[0];   // [2048,1024]
    const float* sup_feat = (const float*)d_in[1];   // [2048,1024]
    const float* pos_emb  = (const float*)d_in[2];   // [1,64,2048,2048]
    const float* Wg_w     = (const float*)d_in[3];   // [16,64]
    const float* Wg_b     = (const float*)d_in[4];   // [16]
    const float* Wq_w     = (const float*)d_in[5];   // [1024,1024]
    const float* Wq_b     = (const float*)d_in[6];   // [1024]
    const float* Wk_w     = (const float*)d_in[7];   // [1024,1024]
    const float* Wk_b     = (const float*)d_in[8];   // [1024]
    float* out = (float*)d_out;                      // [2048,2048]

    // ws layout (floats): q[2M] | k[2M] | wT[1024] | E[4M]  (~33.6 MB)
    float* q  = (float*)d_ws;
    float* k  = q + (size_t)GN * GD;
    float* wT = k + (size_t)GM * GD;
    float* E  = wT + (size_t)GEMB * GHEADS;

    gemm_qk<<<dim3(GD / BN, GN / BM, 2), 256, 0, stream>>>(
        ref_feat, sup_feat, Wq_w, Wq_b, Wk_w, Wk_b, Wg_w, q, k, wT);

    gemm_e<<<dim3(GM / BN, GN / BM), 256, 0, stream>>>(q, k, E);

    gate_out<<<dim3(GM / 1024, GN), 256, 0, stream>>>(pos_emb, E, wT, Wg_b, out);
}